// Round 1
// baseline (1519.051 us; speedup 1.0000x reference)
//
#include <hip/hip_runtime.h>
#include <hip/hip_bf16.h>

#define N_NODES 50000
#define N_EDGES 800000
#define N_GRAPHS 64
#define D 96
#define N_GIN 4
#define BN_EPS 1e-5f

typedef __bf16 bf16;
typedef __bf16 bf16x8 __attribute__((ext_vector_type(8)));
typedef __bf16 bf16x4 __attribute__((ext_vector_type(4)));
typedef float f32x4 __attribute__((ext_vector_type(4)));

// ---------------- init ----------------
__global__ void k_zero(int* deg, float* stats, int nstats) {
    int t = blockIdx.x * blockDim.x + threadIdx.x;
    if (t < N_NODES) deg[t] = 0;
    if (t < nstats) stats[t] = 0.0f;
}

// fp32 h -> bf16 hb
__global__ void k_cast(const float* __restrict__ h, bf16* __restrict__ hb) {
    int t = blockIdx.x * blockDim.x + threadIdx.x;
    int e = t * 4;
    if (e >= N_NODES * D) return;
    float4 v = *(const float4*)(h + e);
    bf16x4 o;
    o[0] = (bf16)v.x; o[1] = (bf16)v.y; o[2] = (bf16)v.z; o[3] = (bf16)v.w;
    *(bf16x4*)(hb + e) = o;
}

// Repack W (fp32 [96][96], k-major) into MFMA B-fragment order, bf16.
// frag f = nt*3+ks (nt in [0,6) n-tile, ks in [0,3) k-step).
// lane l holds B[k=ks*32+(l>>4)*8+j][n=nt*16+(l&15)], j=0..7 contiguous.
__global__ void k_prep(const float* __restrict__ W1, const float* __restrict__ W2,
                       bf16* __restrict__ wf) {
    int mat = blockIdx.x;                      // 0..7
    const float* src = (mat < 4) ? (W1 + mat * D * D) : (W2 + (mat - 4) * D * D);
    bf16* dst = wf + mat * D * D;
    for (int p = threadIdx.x; p < D * D; p += blockDim.x) {
        int f = p >> 9;          // /512
        int r = p & 511;
        int lane = r >> 3;
        int j = r & 7;
        int q = lane >> 4;
        int m16 = lane & 15;
        int nt = f / 3, ks = f % 3;
        int k = ks * 32 + q * 8 + j;
        int n = nt * 16 + m16;
        dst[p] = (bf16)src[k * D + n];
    }
}

// ---------------- CSR build ----------------
__global__ void k_hist(const int* __restrict__ dst, int* __restrict__ deg) {
    int t = blockIdx.x * blockDim.x + threadIdx.x;
    if (t < N_EDGES) atomicAdd(&deg[dst[t]], 1);
}

__global__ void k_scan(const int* __restrict__ deg, int* __restrict__ rowptr,
                       int* __restrict__ cursor) {
    __shared__ int sums[1024];
    int t = threadIdx.x;
    int base = t * 49;
    int cnt = 0;
    if (base < N_NODES) cnt = min(49, N_NODES - base);
    int s = 0;
    for (int j = 0; j < cnt; ++j) s += deg[base + j];
    sums[t] = s;
    __syncthreads();
    for (int off = 1; off < 1024; off <<= 1) {
        int v = 0;
        if (t >= off) v = sums[t - off];
        __syncthreads();
        sums[t] += v;
        __syncthreads();
    }
    int run = sums[t] - s;   // exclusive offset
    for (int j = 0; j < cnt; ++j) {
        rowptr[base + j] = run;
        cursor[base + j] = run;
        run += deg[base + j];
    }
    if (t == 1023) rowptr[N_NODES] = sums[1023];
}

__global__ void k_scatter(const int* __restrict__ src, const int* __restrict__ dst,
                          int* __restrict__ cursor, int* __restrict__ csr_src) {
    int t = blockIdx.x * blockDim.x + threadIdx.x;
    if (t < N_EDGES) {
        int p = atomicAdd(&cursor[dst[t]], 1);
        csr_src[p] = src[t];
    }
}

// ---------------- aggregation: agg[i] = h[i] + sum_{e: dst=i} h[src[e]] ----------------
__global__ void k_agg(const bf16* __restrict__ hb, const int* __restrict__ rowptr,
                      const int* __restrict__ csr_src, bf16* __restrict__ agg) {
    int wid = (blockIdx.x * blockDim.x + threadIdx.x) >> 6;  // one wave per node
    int lane = threadIdx.x & 63;
    if (wid >= N_NODES) return;
    const bf16* row = hb + (size_t)wid * D;
    float s0 = (float)row[lane];
    float s1 = (lane < 32) ? (float)row[64 + lane] : 0.0f;
    int e0 = rowptr[wid], e1 = rowptr[wid + 1];
    for (int e = e0; e < e1; ++e) {
        int sn = csr_src[e];
        const bf16* r2 = hb + (size_t)sn * D;
        s0 += (float)r2[lane];
        if (lane < 32) s1 += (float)r2[64 + lane];
    }
    agg[(size_t)wid * D + lane] = (bf16)s0;
    if (lane < 32) agg[(size_t)wid * D + 64 + lane] = (bf16)s1;
}

// ---------------- persistent-B MFMA GEMM: Z = A @ W + bias, with BN stat accumulation ----
__global__ void __launch_bounds__(256) k_gemm(
        const bf16* __restrict__ A, const bf16* __restrict__ Bf,
        const float* __restrict__ bias, bf16* __restrict__ Z,
        float* __restrict__ ssum, float* __restrict__ sssq) {
    int lane = threadIdx.x & 63;
    int w = (blockIdx.x * blockDim.x + threadIdx.x) >> 6;
    int nw = (gridDim.x * blockDim.x) >> 6;
    int q = lane >> 4, m16 = lane & 15;

    bf16x8 bf[18];
#pragma unroll
    for (int f = 0; f < 18; ++f) bf[f] = *(const bf16x8*)(Bf + (f * 64 + lane) * 8);

    float bv[6];
#pragma unroll
    for (int f = 0; f < 6; ++f) bv[f] = bias[f * 16 + m16];

    float psum[6], pssq[6];
#pragma unroll
    for (int f = 0; f < 6; ++f) { psum[f] = 0.0f; pssq[f] = 0.0f; }

    const int NSTRIP = N_NODES / 16;  // 3125
    for (int s = w; s < NSTRIP; s += nw) {
        const bf16* arow = A + (size_t)(s * 16 + m16) * D;
        bf16x8 a0 = *(const bf16x8*)(arow + q * 8);
        bf16x8 a1 = *(const bf16x8*)(arow + 32 + q * 8);
        bf16x8 a2 = *(const bf16x8*)(arow + 64 + q * 8);
#pragma unroll
        for (int f = 0; f < 6; ++f) {
            f32x4 acc = {0.0f, 0.0f, 0.0f, 0.0f};
            acc = __builtin_amdgcn_mfma_f32_16x16x32_bf16(a0, bf[f * 3 + 0], acc, 0, 0, 0);
            acc = __builtin_amdgcn_mfma_f32_16x16x32_bf16(a1, bf[f * 3 + 1], acc, 0, 0, 0);
            acc = __builtin_amdgcn_mfma_f32_16x16x32_bf16(a2, bf[f * 3 + 2], acc, 0, 0, 0);
            int col = f * 16 + m16;
            bf16* zp = Z + (size_t)(s * 16 + q * 4) * D + col;
#pragma unroll
            for (int i = 0; i < 4; ++i) {
                float v = acc[i] + bv[f];
                zp[(size_t)i * D] = (bf16)v;
                psum[f] += v;
                pssq[f] += v * v;
            }
        }
    }
#pragma unroll
    for (int f = 0; f < 6; ++f) {
        float r = psum[f];
        r += __shfl_xor(r, 16);
        r += __shfl_xor(r, 32);
        float r2 = pssq[f];
        r2 += __shfl_xor(r2, 16);
        r2 += __shfl_xor(r2, 32);
        if (lane < 16) {
            atomicAdd(&ssum[f * 16 + lane], r);
            atomicAdd(&sssq[f * 16 + lane], r2);
        }
    }
}

// ---------------- BN finalize: coef[0..95]=scale, coef[96..191]=shift ----------------
__global__ void k_finalize(const float* __restrict__ ssum, const float* __restrict__ sssq,
                           const float* __restrict__ gamma, const float* __restrict__ beta,
                           float* __restrict__ coef) {
    int c = threadIdx.x;
    if (c >= D) return;
    float m = ssum[c] * (1.0f / N_NODES);
    float v = sssq[c] * (1.0f / N_NODES) - m * m;
    float inv = rsqrtf(v + BN_EPS);
    float sc = gamma[c] * inv;
    coef[c] = sc;
    coef[D + c] = beta[c] - m * sc;
}

// ---------------- elementwise: relu(bn(z)) ----------------
__global__ void k_ew_relu(const bf16* __restrict__ Z, const float* __restrict__ coef,
                          bf16* __restrict__ O) {
    int t = blockIdx.x * blockDim.x + threadIdx.x;
    int e = t * 8;
    if (e >= N_NODES * D) return;
    int c = e % D;
    bf16x8 z = *(const bf16x8*)(Z + e);
    float4 s0 = *(const float4*)(coef + c);
    float4 s1 = *(const float4*)(coef + c + 4);
    float4 t0 = *(const float4*)(coef + D + c);
    float4 t1 = *(const float4*)(coef + D + c + 4);
    bf16x8 o;
    o[0] = (bf16)fmaxf(0.0f, (float)z[0] * s0.x + t0.x);
    o[1] = (bf16)fmaxf(0.0f, (float)z[1] * s0.y + t0.y);
    o[2] = (bf16)fmaxf(0.0f, (float)z[2] * s0.z + t0.z);
    o[3] = (bf16)fmaxf(0.0f, (float)z[3] * s0.w + t0.w);
    o[4] = (bf16)fmaxf(0.0f, (float)z[4] * s1.x + t1.x);
    o[5] = (bf16)fmaxf(0.0f, (float)z[5] * s1.y + t1.y);
    o[6] = (bf16)fmaxf(0.0f, (float)z[6] * s1.z + t1.z);
    o[7] = (bf16)fmaxf(0.0f, (float)z[7] * s1.w + t1.w);
    *(bf16x8*)(O + e) = o;
}

// ---------------- elementwise: prelu(bn(z)) ----------------
__global__ void k_ew_prelu(const bf16* __restrict__ Z, const float* __restrict__ coef,
                           const float* __restrict__ pa, bf16* __restrict__ O) {
    int t = blockIdx.x * blockDim.x + threadIdx.x;
    int e = t * 8;
    if (e >= N_NODES * D) return;
    float alpha = pa[0];
    int c = e % D;
    bf16x8 z = *(const bf16x8*)(Z + e);
    float4 s0 = *(const float4*)(coef + c);
    float4 s1 = *(const float4*)(coef + c + 4);
    float4 t0 = *(const float4*)(coef + D + c);
    float4 t1 = *(const float4*)(coef + D + c + 4);
    float v[8];
    v[0] = (float)z[0] * s0.x + t0.x;
    v[1] = (float)z[1] * s0.y + t0.y;
    v[2] = (float)z[2] * s0.z + t0.z;
    v[3] = (float)z[3] * s0.w + t0.w;
    v[4] = (float)z[4] * s1.x + t1.x;
    v[5] = (float)z[5] * s1.y + t1.y;
    v[6] = (float)z[6] * s1.z + t1.z;
    v[7] = (float)z[7] * s1.w + t1.w;
    bf16x8 o;
#pragma unroll
    for (int j = 0; j < 8; ++j) o[j] = (bf16)(v[j] >= 0.0f ? v[j] : alpha * v[j]);
    *(bf16x8*)(O + e) = o;
}

// ---------------- segment-max pooling (graph ranges are the deterministic partition) ----
__global__ void k_pool(const bf16* __restrict__ hb, float* __restrict__ pooled) {
    int g = blockIdx.x;
    int k = threadIdx.x;
    if (k >= D) return;
    int start = (g * N_NODES + N_GRAPHS - 1) / N_GRAPHS;
    int end = ((g + 1) * N_NODES + N_GRAPHS - 1) / N_GRAPHS;
    float m = -1e30f;
    for (int i = start; i < end; ++i) m = fmaxf(m, (float)hb[(size_t)i * D + k]);
    pooled[g * D + k] = m;
}

// ---------------- head GEMMs: out[g*480 + d*5 + l] = pooled_l[g] @ lin_W[l] + lin_b[l] ----
__global__ void k_heads(const float* __restrict__ pooled, const float* __restrict__ W,
                        const float* __restrict__ B, float* __restrict__ out) {
    int b = blockIdx.x;
    int l = b >> 6;     // 0..4
    int g = b & 63;
    int d = threadIdx.x;
    if (d >= D) return;
    const float* p = pooled + (size_t)(l * N_GRAPHS + g) * D;
    const float* w = W + (size_t)l * D * D;
    float acc = B[l * D + d];
    for (int k = 0; k < D; ++k) acc += p[k] * w[k * D + d];
    out[g * (5 * D) + d * 5 + l] = acc;
}

extern "C" void kernel_launch(void* const* d_in, const int* in_sizes, int n_in,
                              void* d_out, int out_size, void* d_ws, size_t ws_size,
                              hipStream_t stream) {
    const float* h     = (const float*)d_in[0];
    const float* gW1   = (const float*)d_in[1];
    const float* gb1   = (const float*)d_in[2];
    const float* bn1g  = (const float*)d_in[3];
    const float* bn1b  = (const float*)d_in[4];
    const float* gW2   = (const float*)d_in[5];
    const float* gb2   = (const float*)d_in[6];
    const float* bng   = (const float*)d_in[7];
    const float* bnb   = (const float*)d_in[8];
    const float* prelu = (const float*)d_in[9];
    const float* linW  = (const float*)d_in[10];
    const float* linb  = (const float*)d_in[11];
    const int*   srcv  = (const int*)d_in[12];
    const int*   dstv  = (const int*)d_in[13];
    float* out = (float*)d_out;

    // workspace carve (all 256B aligned)
    char* base = (char*)d_ws;
    size_t off = 0;
    auto carve = [&](size_t bytes) -> void* {
        void* p = base + off;
        off += (bytes + 255) & ~(size_t)255;
        return p;
    };
    const size_t HB = (size_t)N_NODES * D;
    bf16* hb0   = (bf16*)carve(HB * 2);
    bf16* hb1   = (bf16*)carve(HB * 2);
    bf16* agg   = (bf16*)carve(HB * 2);
    bf16* zb    = (bf16*)carve(HB * 2);
    bf16* ab    = (bf16*)carve(HB * 2);
    bf16* wf    = (bf16*)carve(8 * D * D * 2);
    float* stats = (float*)carve(N_GIN * 2 * 2 * D * 4);   // [l][stage][sum|ssq][96]
    float* coefs = (float*)carve(N_GIN * 2 * 2 * D * 4);   // [l][stage][scale|shift][96]
    int* rowptr = (int*)carve((N_NODES + 1) * 4);
    int* cursor = (int*)carve(N_NODES * 4);
    int* csr    = (int*)carve((size_t)N_EDGES * 4);
    int* deg    = (int*)carve(N_NODES * 4);
    float* pooled = (float*)carve(5 * N_GRAPHS * D * 4);

    const int NSTATS = N_GIN * 2 * 2 * D;  // 1536

    k_zero<<<196, 256, 0, stream>>>(deg, stats, NSTATS);
    k_cast<<<(N_NODES * D / 4 + 255) / 256, 256, 0, stream>>>(h, hb0);
    k_prep<<<8, 256, 0, stream>>>(gW1, gW2, wf);
    k_hist<<<N_EDGES / 256, 256, 0, stream>>>(dstv, deg);
    k_scan<<<1, 1024, 0, stream>>>(deg, rowptr, cursor);
    k_scatter<<<N_EDGES / 256, 256, 0, stream>>>(srcv, dstv, cursor, csr);
    k_pool<<<N_GRAPHS, 128, 0, stream>>>(hb0, pooled);

    bf16* hcur = hb0;
    bf16* hnext = hb1;
    for (int l = 0; l < N_GIN; ++l) {
        float* st1 = stats + (l * 2 + 0) * 2 * D;
        float* st2 = stats + (l * 2 + 1) * 2 * D;
        float* cf1 = coefs + (l * 2 + 0) * 2 * D;
        float* cf2 = coefs + (l * 2 + 1) * 2 * D;
        k_agg<<<N_NODES / 4, 256, 0, stream>>>(hcur, rowptr, csr, agg);
        k_gemm<<<256, 256, 0, stream>>>(agg, wf + l * D * D, gb1 + l * D, zb, st1, st1 + D);
        k_finalize<<<1, 128, 0, stream>>>(st1, st1 + D, bn1g + l * D, bn1b + l * D, cf1);
        k_ew_relu<<<(N_NODES * D / 8 + 255) / 256, 256, 0, stream>>>(zb, cf1, ab);
        k_gemm<<<256, 256, 0, stream>>>(ab, wf + (4 + l) * D * D, gb2 + l * D, zb, st2, st2 + D);
        k_finalize<<<1, 128, 0, stream>>>(st2, st2 + D, bng + l * D, bnb + l * D, cf2);
        k_ew_prelu<<<(N_NODES * D / 8 + 255) / 256, 256, 0, stream>>>(zb, cf2, prelu, hnext);
        k_pool<<<N_GRAPHS, 128, 0, stream>>>(hnext, pooled + (size_t)(l + 1) * N_GRAPHS * D);
        bf16* tmp = hcur; hcur = hnext; hnext = tmp;
    }
    k_heads<<<5 * N_GRAPHS, 128, 0, stream>>>(pooled, linW, linb, out);
}

// Round 2
// 786.651 us; speedup vs baseline: 1.9310x; 1.9310x over previous
//
#include <hip/hip_runtime.h>
#include <hip/hip_bf16.h>

#define N_NODES 50000
#define N_EDGES 800000
#define N_GRAPHS 64
#define D 96
#define N_GIN 4
#define BN_EPS 1e-5f

typedef __bf16 bf16;
typedef __bf16 bf16x8 __attribute__((ext_vector_type(8)));
typedef __bf16 bf16x4 __attribute__((ext_vector_type(4)));
typedef float f32x4 __attribute__((ext_vector_type(4)));

// ---------------- init ----------------
__global__ void k_zero(int* deg, float* stats, int nstats) {
    int t = blockIdx.x * blockDim.x + threadIdx.x;
    if (t < N_NODES) deg[t] = 0;
    if (t < nstats) stats[t] = 0.0f;
}

// fp32 h -> bf16 hb
__global__ void k_cast(const float* __restrict__ h, bf16* __restrict__ hb) {
    int t = blockIdx.x * blockDim.x + threadIdx.x;
    int e = t * 4;
    if (e >= N_NODES * D) return;
    float4 v = *(const float4*)(h + e);
    bf16x4 o;
    o[0] = (bf16)v.x; o[1] = (bf16)v.y; o[2] = (bf16)v.z; o[3] = (bf16)v.w;
    *(bf16x4*)(hb + e) = o;
}

// Repack W (fp32 [96][96], k-major) into MFMA B-fragment order, bf16.
__global__ void k_prep(const float* __restrict__ W1, const float* __restrict__ W2,
                       bf16* __restrict__ wf) {
    int mat = blockIdx.x;                      // 0..7
    const float* src = (mat < 4) ? (W1 + mat * D * D) : (W2 + (mat - 4) * D * D);
    bf16* dst = wf + mat * D * D;
    for (int p = threadIdx.x; p < D * D; p += blockDim.x) {
        int f = p >> 9;          // /512
        int r = p & 511;
        int lane = r >> 3;
        int j = r & 7;
        int q = lane >> 4;
        int m16 = lane & 15;
        int nt = f / 3, ks = f % 3;
        int k = ks * 32 + q * 8 + j;
        int n = nt * 16 + m16;
        dst[p] = (bf16)src[k * D + n];
    }
}

// ---------------- CSR build ----------------
__global__ void k_hist(const int* __restrict__ dst, int* __restrict__ deg) {
    int t = blockIdx.x * blockDim.x + threadIdx.x;
    if (t < N_EDGES) atomicAdd(&deg[dst[t]], 1);
}

__global__ void k_scan(const int* __restrict__ deg, int* __restrict__ rowptr,
                       int* __restrict__ cursor) {
    __shared__ int sums[1024];
    int t = threadIdx.x;
    int base = t * 49;
    int cnt = 0;
    if (base < N_NODES) cnt = min(49, N_NODES - base);
    int s = 0;
    for (int j = 0; j < cnt; ++j) s += deg[base + j];
    sums[t] = s;
    __syncthreads();
    for (int off = 1; off < 1024; off <<= 1) {
        int v = 0;
        if (t >= off) v = sums[t - off];
        __syncthreads();
        sums[t] += v;
        __syncthreads();
    }
    int run = sums[t] - s;   // exclusive offset
    for (int j = 0; j < cnt; ++j) {
        rowptr[base + j] = run;
        cursor[base + j] = run;
        run += deg[base + j];
    }
    if (t == 1023) rowptr[N_NODES] = sums[1023];
}

__global__ void k_scatter(const int* __restrict__ src, const int* __restrict__ dst,
                          int* __restrict__ cursor, int* __restrict__ csr_src) {
    int t = blockIdx.x * blockDim.x + threadIdx.x;
    if (t < N_EDGES) {
        int p = atomicAdd(&cursor[dst[t]], 1);
        csr_src[p] = src[t];
    }
}

// ---------------- aggregation: agg[i] = h[i] + sum_{e: dst=i} h[src[e]] ----------------
// 16 nodes per 256-thread block; 16-lane group per node, 12 active lanes,
// bf16x8 (16B) loads, edge loop unrolled x4 for memory-level parallelism.
__global__ void __launch_bounds__(256) k_agg(
        const bf16* __restrict__ hb, const int* __restrict__ rowptr,
        const int* __restrict__ csr_src, bf16* __restrict__ agg) {
    int node = blockIdx.x * 16 + (threadIdx.x >> 4);
    int l = threadIdx.x & 15;
    if (l >= 12) return;                       // 12 lanes x 8 cols = 96
    const bf16x8* __restrict__ base = (const bf16x8*)hb;   // row = 12 vectors
    float acc[8];
    bf16x8 self = base[node * 12 + l];
#pragma unroll
    for (int j = 0; j < 8; ++j) acc[j] = (float)self[j];
    int e0 = rowptr[node], e1 = rowptr[node + 1];
    int e = e0;
    for (; e + 4 <= e1; e += 4) {
        int s0 = csr_src[e];
        int s1 = csr_src[e + 1];
        int s2 = csr_src[e + 2];
        int s3 = csr_src[e + 3];
        bf16x8 r0 = base[s0 * 12 + l];
        bf16x8 r1 = base[s1 * 12 + l];
        bf16x8 r2 = base[s2 * 12 + l];
        bf16x8 r3 = base[s3 * 12 + l];
#pragma unroll
        for (int j = 0; j < 8; ++j) {
            acc[j] += (float)r0[j];
            acc[j] += (float)r1[j];
            acc[j] += (float)r2[j];
            acc[j] += (float)r3[j];
        }
    }
    for (; e < e1; ++e) {
        int s = csr_src[e];
        bf16x8 r = base[s * 12 + l];
#pragma unroll
        for (int j = 0; j < 8; ++j) acc[j] += (float)r[j];
    }
    bf16x8 o;
#pragma unroll
    for (int j = 0; j < 8; ++j) o[j] = (bf16)acc[j];
    ((bf16x8*)agg)[node * 12 + l] = o;
}

// ---------------- persistent-B MFMA GEMM: Z = A @ W + bias, with BN stat accumulation ----
__global__ void __launch_bounds__(256) k_gemm(
        const bf16* __restrict__ A, const bf16* __restrict__ Bf,
        const float* __restrict__ bias, bf16* __restrict__ Z,
        float* __restrict__ ssum, float* __restrict__ sssq) {
    int lane = threadIdx.x & 63;
    int w = (blockIdx.x * blockDim.x + threadIdx.x) >> 6;
    int nw = (gridDim.x * blockDim.x) >> 6;
    int q = lane >> 4, m16 = lane & 15;

    bf16x8 bf[18];
#pragma unroll
    for (int f = 0; f < 18; ++f) bf[f] = *(const bf16x8*)(Bf + (f * 64 + lane) * 8);

    float bv[6];
#pragma unroll
    for (int f = 0; f < 6; ++f) bv[f] = bias[f * 16 + m16];

    float psum[6], pssq[6];
#pragma unroll
    for (int f = 0; f < 6; ++f) { psum[f] = 0.0f; pssq[f] = 0.0f; }

    const int NSTRIP = N_NODES / 16;  // 3125
    for (int s = w; s < NSTRIP; s += nw) {
        const bf16* arow = A + (size_t)(s * 16 + m16) * D;
        bf16x8 a0 = *(const bf16x8*)(arow + q * 8);
        bf16x8 a1 = *(const bf16x8*)(arow + 32 + q * 8);
        bf16x8 a2 = *(const bf16x8*)(arow + 64 + q * 8);
#pragma unroll
        for (int f = 0; f < 6; ++f) {
            f32x4 acc = {0.0f, 0.0f, 0.0f, 0.0f};
            acc = __builtin_amdgcn_mfma_f32_16x16x32_bf16(a0, bf[f * 3 + 0], acc, 0, 0, 0);
            acc = __builtin_amdgcn_mfma_f32_16x16x32_bf16(a1, bf[f * 3 + 1], acc, 0, 0, 0);
            acc = __builtin_amdgcn_mfma_f32_16x16x32_bf16(a2, bf[f * 3 + 2], acc, 0, 0, 0);
            int col = f * 16 + m16;
            bf16* zp = Z + (size_t)(s * 16 + q * 4) * D + col;
#pragma unroll
            for (int i = 0; i < 4; ++i) {
                float v = acc[i] + bv[f];
                zp[(size_t)i * D] = (bf16)v;
                psum[f] += v;
                pssq[f] += v * v;
            }
        }
    }
#pragma unroll
    for (int f = 0; f < 6; ++f) {
        float r = psum[f];
        r += __shfl_xor(r, 16);
        r += __shfl_xor(r, 32);
        float r2 = pssq[f];
        r2 += __shfl_xor(r2, 16);
        r2 += __shfl_xor(r2, 32);
        if (lane < 16) {
            atomicAdd(&ssum[f * 16 + lane], r);
            atomicAdd(&sssq[f * 16 + lane], r2);
        }
    }
}

// ---------------- BN finalize: coef[0..95]=scale, coef[96..191]=shift ----------------
__global__ void k_finalize(const float* __restrict__ ssum, const float* __restrict__ sssq,
                           const float* __restrict__ gamma, const float* __restrict__ beta,
                           float* __restrict__ coef) {
    int c = threadIdx.x;
    if (c >= D) return;
    float m = ssum[c] * (1.0f / N_NODES);
    float v = sssq[c] * (1.0f / N_NODES) - m * m;
    float inv = rsqrtf(v + BN_EPS);
    float sc = gamma[c] * inv;
    coef[c] = sc;
    coef[D + c] = beta[c] - m * sc;
}

// ---------------- elementwise: relu(bn(z)) ----------------
__global__ void k_ew_relu(const bf16* __restrict__ Z, const float* __restrict__ coef,
                          bf16* __restrict__ O) {
    int t = blockIdx.x * blockDim.x + threadIdx.x;
    int e = t * 8;
    if (e >= N_NODES * D) return;
    int c = e % D;
    bf16x8 z = *(const bf16x8*)(Z + e);
    float4 s0 = *(const float4*)(coef + c);
    float4 s1 = *(const float4*)(coef + c + 4);
    float4 t0 = *(const float4*)(coef + D + c);
    float4 t1 = *(const float4*)(coef + D + c + 4);
    bf16x8 o;
    o[0] = (bf16)fmaxf(0.0f, (float)z[0] * s0.x + t0.x);
    o[1] = (bf16)fmaxf(0.0f, (float)z[1] * s0.y + t0.y);
    o[2] = (bf16)fmaxf(0.0f, (float)z[2] * s0.z + t0.z);
    o[3] = (bf16)fmaxf(0.0f, (float)z[3] * s0.w + t0.w);
    o[4] = (bf16)fmaxf(0.0f, (float)z[4] * s1.x + t1.x);
    o[5] = (bf16)fmaxf(0.0f, (float)z[5] * s1.y + t1.y);
    o[6] = (bf16)fmaxf(0.0f, (float)z[6] * s1.z + t1.z);
    o[7] = (bf16)fmaxf(0.0f, (float)z[7] * s1.w + t1.w);
    *(bf16x8*)(O + e) = o;
}

// ---------------- elementwise: prelu(bn(z)) ----------------
__global__ void k_ew_prelu(const bf16* __restrict__ Z, const float* __restrict__ coef,
                           const float* __restrict__ pa, bf16* __restrict__ O) {
    int t = blockIdx.x * blockDim.x + threadIdx.x;
    int e = t * 8;
    if (e >= N_NODES * D) return;
    float alpha = pa[0];
    int c = e % D;
    bf16x8 z = *(const bf16x8*)(Z + e);
    float4 s0 = *(const float4*)(coef + c);
    float4 s1 = *(const float4*)(coef + c + 4);
    float4 t0 = *(const float4*)(coef + D + c);
    float4 t1 = *(const float4*)(coef + D + c + 4);
    float v[8];
    v[0] = (float)z[0] * s0.x + t0.x;
    v[1] = (float)z[1] * s0.y + t0.y;
    v[2] = (float)z[2] * s0.z + t0.z;
    v[3] = (float)z[3] * s0.w + t0.w;
    v[4] = (float)z[4] * s1.x + t1.x;
    v[5] = (float)z[5] * s1.y + t1.y;
    v[6] = (float)z[6] * s1.z + t1.z;
    v[7] = (float)z[7] * s1.w + t1.w;
    bf16x8 o;
#pragma unroll
    for (int j = 0; j < 8; ++j) o[j] = (bf16)(v[j] >= 0.0f ? v[j] : alpha * v[j]);
    *(bf16x8*)(O + e) = o;
}

// ---------------- two-stage segment-max pooling ----------------
// stage 1: 16 chunks per graph -> partial max [64][16][96]
__global__ void k_pool1(const bf16* __restrict__ hb, float* __restrict__ part) {
    int g = blockIdx.x >> 4;
    int c = blockIdx.x & 15;
    int k = threadIdx.x;
    if (k >= D) return;
    int gs = (g * N_NODES + N_GRAPHS - 1) / N_GRAPHS;
    int ge = ((g + 1) * N_NODES + N_GRAPHS - 1) / N_GRAPHS;
    int len = ge - gs;
    int cs = gs + (len * c) / 16;
    int ce = gs + (len * (c + 1)) / 16;
    float m = -1e30f;
    for (int i = cs; i < ce; ++i) m = fmaxf(m, (float)hb[(size_t)i * D + k]);
    part[(size_t)(g * 16 + c) * D + k] = m;
}

// stage 2: reduce 16 chunks -> pooled [64][96]
__global__ void k_pool2(const float* __restrict__ part, float* __restrict__ pooled) {
    int g = blockIdx.x;
    int k = threadIdx.x;
    if (k >= D) return;
    float m = part[(size_t)(g * 16) * D + k];
#pragma unroll
    for (int c = 1; c < 16; ++c) m = fmaxf(m, part[(size_t)(g * 16 + c) * D + k]);
    pooled[(size_t)g * D + k] = m;
}

// ---------------- head GEMMs ----------------
__global__ void k_heads(const float* __restrict__ pooled, const float* __restrict__ W,
                        const float* __restrict__ B, float* __restrict__ out) {
    int b = blockIdx.x;
    int l = b >> 6;     // 0..4
    int g = b & 63;
    int d = threadIdx.x;
    if (d >= D) return;
    const float* p = pooled + (size_t)(l * N_GRAPHS + g) * D;
    const float* w = W + (size_t)l * D * D;
    float acc = B[l * D + d];
    for (int k = 0; k < D; ++k) acc += p[k] * w[k * D + d];
    out[g * (5 * D) + d * 5 + l] = acc;
}

extern "C" void kernel_launch(void* const* d_in, const int* in_sizes, int n_in,
                              void* d_out, int out_size, void* d_ws, size_t ws_size,
                              hipStream_t stream) {
    const float* h     = (const float*)d_in[0];
    const float* gW1   = (const float*)d_in[1];
    const float* gb1   = (const float*)d_in[2];
    const float* bn1g  = (const float*)d_in[3];
    const float* bn1b  = (const float*)d_in[4];
    const float* gW2   = (const float*)d_in[5];
    const float* gb2   = (const float*)d_in[6];
    const float* bng   = (const float*)d_in[7];
    const float* bnb   = (const float*)d_in[8];
    const float* prelu = (const float*)d_in[9];
    const float* linW  = (const float*)d_in[10];
    const float* linb  = (const float*)d_in[11];
    const int*   srcv  = (const int*)d_in[12];
    const int*   dstv  = (const int*)d_in[13];
    float* out = (float*)d_out;

    char* base = (char*)d_ws;
    size_t off = 0;
    auto carve = [&](size_t bytes) -> void* {
        void* p = base + off;
        off += (bytes + 255) & ~(size_t)255;
        return p;
    };
    const size_t HB = (size_t)N_NODES * D;
    bf16* hb0   = (bf16*)carve(HB * 2);
    bf16* hb1   = (bf16*)carve(HB * 2);
    bf16* agg   = (bf16*)carve(HB * 2);
    bf16* zb    = (bf16*)carve(HB * 2);
    bf16* ab    = (bf16*)carve(HB * 2);
    bf16* wf    = (bf16*)carve(8 * D * D * 2);
    float* stats = (float*)carve(N_GIN * 2 * 2 * D * 4);
    float* coefs = (float*)carve(N_GIN * 2 * 2 * D * 4);
    int* rowptr = (int*)carve((N_NODES + 1) * 4);
    int* cursor = (int*)carve(N_NODES * 4);
    int* csr    = (int*)carve((size_t)N_EDGES * 4);
    int* deg    = (int*)carve(N_NODES * 4);
    float* pooled = (float*)carve(5 * N_GRAPHS * D * 4);
    float* part   = (float*)carve((size_t)N_GRAPHS * 16 * D * 4);

    const int NSTATS = N_GIN * 2 * 2 * D;  // 1536

    k_zero<<<196, 256, 0, stream>>>(deg, stats, NSTATS);
    k_cast<<<(N_NODES * D / 4 + 255) / 256, 256, 0, stream>>>(h, hb0);
    k_prep<<<8, 256, 0, stream>>>(gW1, gW2, wf);
    k_hist<<<N_EDGES / 256, 256, 0, stream>>>(dstv, deg);
    k_scan<<<1, 1024, 0, stream>>>(deg, rowptr, cursor);
    k_scatter<<<N_EDGES / 256, 256, 0, stream>>>(srcv, dstv, cursor, csr);
    k_pool1<<<N_GRAPHS * 16, 96, 0, stream>>>(hb0, part);
    k_pool2<<<N_GRAPHS, 96, 0, stream>>>(part, pooled);

    bf16* hcur = hb0;
    bf16* hnext = hb1;
    for (int l = 0; l < N_GIN; ++l) {
        float* st1 = stats + (l * 2 + 0) * 2 * D;
        float* st2 = stats + (l * 2 + 1) * 2 * D;
        float* cf1 = coefs + (l * 2 + 0) * 2 * D;
        float* cf2 = coefs + (l * 2 + 1) * 2 * D;
        k_agg<<<N_NODES / 16, 256, 0, stream>>>(hcur, rowptr, csr, agg);
        k_gemm<<<256, 256, 0, stream>>>(agg, wf + l * D * D, gb1 + l * D, zb, st1, st1 + D);
        k_finalize<<<1, 128, 0, stream>>>(st1, st1 + D, bn1g + l * D, bn1b + l * D, cf1);
        k_ew_relu<<<(N_NODES * D / 8 + 255) / 256, 256, 0, stream>>>(zb, cf1, ab);
        k_gemm<<<256, 256, 0, stream>>>(ab, wf + (4 + l) * D * D, gb2 + l * D, zb, st2, st2 + D);
        k_finalize<<<1, 128, 0, stream>>>(st2, st2 + D, bng + l * D, bnb + l * D, cf2);
        k_ew_prelu<<<(N_NODES * D / 8 + 255) / 256, 256, 0, stream>>>(zb, cf2, prelu, hnext);
        k_pool1<<<N_GRAPHS * 16, 96, 0, stream>>>(hnext, part);
        k_pool2<<<N_GRAPHS, 96, 0, stream>>>(part, pooled + (size_t)(l + 1) * N_GRAPHS * D);
        bf16* tmp = hcur; hcur = hnext; hnext = tmp;
    }
    k_heads<<<5 * N_GRAPHS, 128, 0, stream>>>(pooled, linW, linb, out);
}

// Round 3
// 658.860 us; speedup vs baseline: 2.3056x; 1.1940x over previous
//
#include <hip/hip_runtime.h>
#include <hip/hip_bf16.h>

#define N_NODES 50000
#define N_EDGES 800000
#define N_GRAPHS 64
#define D 96
#define N_GIN 4
#define BN_EPS 1e-5f
#define NB 196          // scan blocks: 196*256 >= 50000
#define PCH 64          // pool chunks per graph

typedef __bf16 bf16;
typedef __bf16 bf16x8 __attribute__((ext_vector_type(8)));
typedef __bf16 bf16x4 __attribute__((ext_vector_type(4)));
typedef float f32x4 __attribute__((ext_vector_type(4)));

// ---------------- init ----------------
__global__ void k_zero(int* deg, float* stats, int nstats) {
    int t = blockIdx.x * blockDim.x + threadIdx.x;
    if (t < N_NODES) deg[t] = 0;
    if (t < nstats) stats[t] = 0.0f;
}

// fp32 h -> bf16 hb
__global__ void k_cast(const float* __restrict__ h, bf16* __restrict__ hb) {
    int t = blockIdx.x * blockDim.x + threadIdx.x;
    int e = t * 4;
    if (e >= N_NODES * D) return;
    float4 v = *(const float4*)(h + e);
    bf16x4 o;
    o[0] = (bf16)v.x; o[1] = (bf16)v.y; o[2] = (bf16)v.z; o[3] = (bf16)v.w;
    *(bf16x4*)(hb + e) = o;
}

// Repack W (fp32 [96][96], k-major) into MFMA B-fragment order, bf16.
__global__ void k_prep(const float* __restrict__ W1, const float* __restrict__ W2,
                       bf16* __restrict__ wf) {
    int mat = blockIdx.x;                      // 0..7
    const float* src = (mat < 4) ? (W1 + mat * D * D) : (W2 + (mat - 4) * D * D);
    bf16* dst = wf + mat * D * D;
    for (int p = threadIdx.x; p < D * D; p += blockDim.x) {
        int f = p >> 9;
        int r = p & 511;
        int lane = r >> 3;
        int j = r & 7;
        int q = lane >> 4;
        int m16 = lane & 15;
        int nt = f / 3, ks = f % 3;
        int k = ks * 32 + q * 8 + j;
        int n = nt * 16 + m16;
        dst[p] = (bf16)src[k * D + n];
    }
}

// ---------------- CSR build ----------------
__global__ void k_hist(const int* __restrict__ dst, int* __restrict__ deg) {
    int t = blockIdx.x * blockDim.x + threadIdx.x;
    if (t < N_EDGES) atomicAdd(&deg[dst[t]], 1);
}

// stage 1: per-block exclusive scan of 256 degrees + block total
__global__ void k_scan1(const int* __restrict__ deg, int* __restrict__ tmp,
                        int* __restrict__ bsum) {
    __shared__ int s[256];
    int t = threadIdx.x;
    int i = blockIdx.x * 256 + t;
    int v = (i < N_NODES) ? deg[i] : 0;
    s[t] = v;
    __syncthreads();
    for (int off = 1; off < 256; off <<= 1) {
        int u = (t >= off) ? s[t - off] : 0;
        __syncthreads();
        s[t] += u;
        __syncthreads();
    }
    if (i < N_NODES) tmp[i] = s[t] - v;        // exclusive
    if (t == 255) bsum[blockIdx.x] = s[255];
}

// stage 2: scan the 196 block sums (one block)
__global__ void k_scan2(const int* __restrict__ bsum, int* __restrict__ bpre) {
    __shared__ int s[256];
    int t = threadIdx.x;
    int v = (t < NB) ? bsum[t] : 0;
    s[t] = v;
    __syncthreads();
    for (int off = 1; off < 256; off <<= 1) {
        int u = (t >= off) ? s[t - off] : 0;
        __syncthreads();
        s[t] += u;
        __syncthreads();
    }
    if (t < NB) bpre[t] = s[t] - v;            // exclusive
}

// stage 3: add block offsets, emit rowptr + cursor
__global__ void k_scan3(const int* __restrict__ tmp, const int* __restrict__ bpre,
                        int* __restrict__ rowptr, int* __restrict__ cursor) {
    int i = blockIdx.x * 256 + threadIdx.x;
    if (i < N_NODES) {
        int r = tmp[i] + bpre[blockIdx.x];
        rowptr[i] = r;
        cursor[i] = r;
    }
    if (i == 0) rowptr[N_NODES] = N_EDGES;
}

__global__ void k_scatter(const int* __restrict__ src, const int* __restrict__ dst,
                          int* __restrict__ cursor, int* __restrict__ csr_src) {
    int t = blockIdx.x * blockDim.x + threadIdx.x;
    if (t < N_EDGES) {
        int p = atomicAdd(&cursor[dst[t]], 1);
        csr_src[p] = src[t];
    }
}

// ---------------- aggregation: agg[i] = h[i] + sum_{e: dst=i} h[src[e]] ----------------
// 16 nodes per 256-thread block; 16-lane group per node, 12 active lanes,
// bf16x8 (16B) loads, edge loop unrolled x8 for memory-level parallelism.
__global__ void __launch_bounds__(256) k_agg(
        const bf16* __restrict__ hb, const int* __restrict__ rowptr,
        const int* __restrict__ csr_src, bf16* __restrict__ agg) {
    int node = blockIdx.x * 16 + (threadIdx.x >> 4);
    int l = threadIdx.x & 15;
    if (l >= 12) return;                       // 12 lanes x 8 cols = 96
    const bf16x8* __restrict__ base = (const bf16x8*)hb;
    float acc[8];
    bf16x8 self = base[node * 12 + l];
#pragma unroll
    for (int j = 0; j < 8; ++j) acc[j] = (float)self[j];
    int e0 = rowptr[node], e1 = rowptr[node + 1];
    int e = e0;
    for (; e + 8 <= e1; e += 8) {
        int s0 = csr_src[e];
        int s1 = csr_src[e + 1];
        int s2 = csr_src[e + 2];
        int s3 = csr_src[e + 3];
        int s4 = csr_src[e + 4];
        int s5 = csr_src[e + 5];
        int s6 = csr_src[e + 6];
        int s7 = csr_src[e + 7];
        bf16x8 r0 = base[s0 * 12 + l];
        bf16x8 r1 = base[s1 * 12 + l];
        bf16x8 r2 = base[s2 * 12 + l];
        bf16x8 r3 = base[s3 * 12 + l];
        bf16x8 r4 = base[s4 * 12 + l];
        bf16x8 r5 = base[s5 * 12 + l];
        bf16x8 r6 = base[s6 * 12 + l];
        bf16x8 r7 = base[s7 * 12 + l];
#pragma unroll
        for (int j = 0; j < 8; ++j) {
            acc[j] += (float)r0[j] + (float)r1[j] + (float)r2[j] + (float)r3[j]
                    + (float)r4[j] + (float)r5[j] + (float)r6[j] + (float)r7[j];
        }
    }
    for (; e + 2 <= e1; e += 2) {
        int s0 = csr_src[e];
        int s1 = csr_src[e + 1];
        bf16x8 r0 = base[s0 * 12 + l];
        bf16x8 r1 = base[s1 * 12 + l];
#pragma unroll
        for (int j = 0; j < 8; ++j) acc[j] += (float)r0[j] + (float)r1[j];
    }
    if (e < e1) {
        int s = csr_src[e];
        bf16x8 r = base[s * 12 + l];
#pragma unroll
        for (int j = 0; j < 8; ++j) acc[j] += (float)r[j];
    }
    bf16x8 o;
#pragma unroll
    for (int j = 0; j < 8; ++j) o[j] = (bf16)acc[j];
    ((bf16x8*)agg)[node * 12 + l] = o;
}

// ---------------- GEMM1: Z = A @ W + bias, accumulate BN stats ----------------
__global__ void __launch_bounds__(256) k_gemm(
        const bf16* __restrict__ A, const bf16* __restrict__ Bf,
        const float* __restrict__ bias, bf16* __restrict__ Z,
        float* __restrict__ ssum, float* __restrict__ sssq) {
    int lane = threadIdx.x & 63;
    int w = (blockIdx.x * blockDim.x + threadIdx.x) >> 6;
    int nw = (gridDim.x * blockDim.x) >> 6;
    int q = lane >> 4, m16 = lane & 15;

    bf16x8 bfr[18];
#pragma unroll
    for (int f = 0; f < 18; ++f) bfr[f] = *(const bf16x8*)(Bf + (f * 64 + lane) * 8);

    float bv[6];
#pragma unroll
    for (int f = 0; f < 6; ++f) bv[f] = bias[f * 16 + m16];

    float psum[6], pssq[6];
#pragma unroll
    for (int f = 0; f < 6; ++f) { psum[f] = 0.0f; pssq[f] = 0.0f; }

    const int NSTRIP = N_NODES / 16;  // 3125
    for (int s = w; s < NSTRIP; s += nw) {
        const bf16* arow = A + (size_t)(s * 16 + m16) * D;
        bf16x8 a0 = *(const bf16x8*)(arow + q * 8);
        bf16x8 a1 = *(const bf16x8*)(arow + 32 + q * 8);
        bf16x8 a2 = *(const bf16x8*)(arow + 64 + q * 8);
#pragma unroll
        for (int f = 0; f < 6; ++f) {
            f32x4 acc = {0.0f, 0.0f, 0.0f, 0.0f};
            acc = __builtin_amdgcn_mfma_f32_16x16x32_bf16(a0, bfr[f * 3 + 0], acc, 0, 0, 0);
            acc = __builtin_amdgcn_mfma_f32_16x16x32_bf16(a1, bfr[f * 3 + 1], acc, 0, 0, 0);
            acc = __builtin_amdgcn_mfma_f32_16x16x32_bf16(a2, bfr[f * 3 + 2], acc, 0, 0, 0);
            int col = f * 16 + m16;
            bf16* zp = Z + (size_t)(s * 16 + q * 4) * D + col;
#pragma unroll
            for (int i = 0; i < 4; ++i) {
                float v = acc[i] + bv[f];
                zp[(size_t)i * D] = (bf16)v;
                psum[f] += v;
                pssq[f] += v * v;
            }
        }
    }
#pragma unroll
    for (int f = 0; f < 6; ++f) {
        float r = psum[f];
        r += __shfl_xor(r, 16);
        r += __shfl_xor(r, 32);
        float r2 = pssq[f];
        r2 += __shfl_xor(r2, 16);
        r2 += __shfl_xor(r2, 32);
        if (lane < 16) {
            atomicAdd(&ssum[f * 16 + lane], r);
            atomicAdd(&sssq[f * 16 + lane], r2);
        }
    }
}

// ---------------- GEMM2 fused: finalize BN1 from stats, apply affine+ReLU to A
// on the fly, Z2 = relu(bn1(Z1)) @ W2 + b2, accumulate BN2 stats ----------------
__global__ void __launch_bounds__(256) k_gemm_fused(
        const bf16* __restrict__ A, const bf16* __restrict__ Bf,
        const float* __restrict__ st,   // [2*D]: sum, ssq of Z1
        const float* __restrict__ gamma, const float* __restrict__ beta,
        const float* __restrict__ bias, bf16* __restrict__ Z,
        float* __restrict__ ssum, float* __restrict__ sssq) {
    __shared__ float cs[D], ct[D];
    int tid = threadIdx.x;
    if (tid < D) {
        float m = st[tid] * (1.0f / N_NODES);
        float v = st[D + tid] * (1.0f / N_NODES) - m * m;
        float inv = rsqrtf(v + BN_EPS);
        float sc = gamma[tid] * inv;
        cs[tid] = sc;
        ct[tid] = beta[tid] - m * sc;
    }
    __syncthreads();

    int lane = tid & 63;
    int w = (blockIdx.x * blockDim.x + tid) >> 6;
    int nw = (gridDim.x * blockDim.x) >> 6;
    int q = lane >> 4, m16 = lane & 15;

    float as_[3][8], at_[3][8];
#pragma unroll
    for (int ks = 0; ks < 3; ++ks)
#pragma unroll
        for (int j = 0; j < 8; ++j) {
            as_[ks][j] = cs[ks * 32 + q * 8 + j];
            at_[ks][j] = ct[ks * 32 + q * 8 + j];
        }

    bf16x8 bfr[18];
#pragma unroll
    for (int f = 0; f < 18; ++f) bfr[f] = *(const bf16x8*)(Bf + (f * 64 + lane) * 8);

    float bv[6];
#pragma unroll
    for (int f = 0; f < 6; ++f) bv[f] = bias[f * 16 + m16];

    float psum[6], pssq[6];
#pragma unroll
    for (int f = 0; f < 6; ++f) { psum[f] = 0.0f; pssq[f] = 0.0f; }

    const int NSTRIP = N_NODES / 16;
    for (int s = w; s < NSTRIP; s += nw) {
        const bf16* arow = A + (size_t)(s * 16 + m16) * D;
        bf16x8 z0 = *(const bf16x8*)(arow + q * 8);
        bf16x8 z1 = *(const bf16x8*)(arow + 32 + q * 8);
        bf16x8 z2 = *(const bf16x8*)(arow + 64 + q * 8);
        bf16x8 a0, a1, a2;
#pragma unroll
        for (int j = 0; j < 8; ++j) {
            a0[j] = (bf16)fmaxf(0.0f, (float)z0[j] * as_[0][j] + at_[0][j]);
            a1[j] = (bf16)fmaxf(0.0f, (float)z1[j] * as_[1][j] + at_[1][j]);
            a2[j] = (bf16)fmaxf(0.0f, (float)z2[j] * as_[2][j] + at_[2][j]);
        }
#pragma unroll
        for (int f = 0; f < 6; ++f) {
            f32x4 acc = {0.0f, 0.0f, 0.0f, 0.0f};
            acc = __builtin_amdgcn_mfma_f32_16x16x32_bf16(a0, bfr[f * 3 + 0], acc, 0, 0, 0);
            acc = __builtin_amdgcn_mfma_f32_16x16x32_bf16(a1, bfr[f * 3 + 1], acc, 0, 0, 0);
            acc = __builtin_amdgcn_mfma_f32_16x16x32_bf16(a2, bfr[f * 3 + 2], acc, 0, 0, 0);
            int col = f * 16 + m16;
            bf16* zp = Z + (size_t)(s * 16 + q * 4) * D + col;
#pragma unroll
            for (int i = 0; i < 4; ++i) {
                float v = acc[i] + bv[f];
                zp[(size_t)i * D] = (bf16)v;
                psum[f] += v;
                pssq[f] += v * v;
            }
        }
    }
#pragma unroll
    for (int f = 0; f < 6; ++f) {
        float r = psum[f];
        r += __shfl_xor(r, 16);
        r += __shfl_xor(r, 32);
        float r2 = pssq[f];
        r2 += __shfl_xor(r2, 16);
        r2 += __shfl_xor(r2, 32);
        if (lane < 16) {
            atomicAdd(&ssum[f * 16 + lane], r);
            atomicAdd(&sssq[f * 16 + lane], r2);
        }
    }
}

// ---------------- elementwise: prelu(bn2(z)), finalize fused ----------------
__global__ void k_ew_prelu(const bf16* __restrict__ Z, const float* __restrict__ st,
                           const float* __restrict__ gamma, const float* __restrict__ beta,
                           const float* __restrict__ pa, bf16* __restrict__ O) {
    __shared__ float cs[D], ct[D];
    int t = threadIdx.x;
    if (t < D) {
        float m = st[t] * (1.0f / N_NODES);
        float v = st[D + t] * (1.0f / N_NODES) - m * m;
        float inv = rsqrtf(v + BN_EPS);
        float sc = gamma[t] * inv;
        cs[t] = sc;
        ct[t] = beta[t] - m * sc;
    }
    __syncthreads();
    int e = (blockIdx.x * blockDim.x + t) * 8;
    if (e >= N_NODES * D) return;
    float alpha = pa[0];
    int c = e % D;
    bf16x8 z = *(const bf16x8*)(Z + e);
    bf16x8 o;
#pragma unroll
    for (int j = 0; j < 8; ++j) {
        float v = (float)z[j] * cs[c + j] + ct[c + j];
        o[j] = (bf16)(v >= 0.0f ? v : alpha * v);
    }
    *(bf16x8*)(O + e) = o;
}

// ---------------- two-stage segment-max pooling, vectorized ----------------
// stage 1: PCH chunks per graph; 16-lane groups (12 active), bf16x8 loads
__global__ void __launch_bounds__(256) k_pool1(const bf16* __restrict__ hb,
                                               float* __restrict__ part) {
    int grp = blockIdx.x * 16 + (threadIdx.x >> 4);   // chunk id, 0..N_GRAPHS*PCH-1
    int l = threadIdx.x & 15;
    if (l >= 12) return;
    int g = grp / PCH, c = grp % PCH;
    int gs = (g * N_NODES + N_GRAPHS - 1) / N_GRAPHS;
    int ge = ((g + 1) * N_NODES + N_GRAPHS - 1) / N_GRAPHS;
    int len = ge - gs;
    int rs = gs + (len * c) / PCH;
    int re = gs + (len * (c + 1)) / PCH;
    const bf16x8* __restrict__ base = (const bf16x8*)hb;
    float m[8];
#pragma unroll
    for (int j = 0; j < 8; ++j) m[j] = -3e38f;
    int i = rs;
    for (; i + 2 <= re; i += 2) {
        bf16x8 r0 = base[i * 12 + l];
        bf16x8 r1 = base[(i + 1) * 12 + l];
#pragma unroll
        for (int j = 0; j < 8; ++j) m[j] = fmaxf(m[j], fmaxf((float)r0[j], (float)r1[j]));
    }
    if (i < re) {
        bf16x8 r = base[i * 12 + l];
#pragma unroll
        for (int j = 0; j < 8; ++j) m[j] = fmaxf(m[j], (float)r[j]);
    }
    float* dst = part + (size_t)grp * D + l * 8;
    *(float4*)dst = make_float4(m[0], m[1], m[2], m[3]);
    *(float4*)(dst + 4) = make_float4(m[4], m[5], m[6], m[7]);
}

// stage 2: reduce PCH chunks -> pooled [64][96]
__global__ void k_pool2(const float* __restrict__ part, float* __restrict__ pooled) {
    int g = blockIdx.x;
    int k = threadIdx.x;
    if (k >= D) return;
    float m = -3e38f;
    for (int c = 0; c < PCH; ++c) m = fmaxf(m, part[(size_t)(g * PCH + c) * D + k]);
    pooled[(size_t)g * D + k] = m;
}

// ---------------- head GEMMs ----------------
__global__ void k_heads(const float* __restrict__ pooled, const float* __restrict__ W,
                        const float* __restrict__ B, float* __restrict__ out) {
    int b = blockIdx.x;
    int l = b >> 6;     // 0..4
    int g = b & 63;
    int d = threadIdx.x;
    if (d >= D) return;
    const float* p = pooled + (size_t)(l * N_GRAPHS + g) * D;
    const float* w = W + (size_t)l * D * D;
    float acc = B[l * D + d];
    for (int k = 0; k < D; ++k) acc += p[k] * w[k * D + d];
    out[g * (5 * D) + d * 5 + l] = acc;
}

extern "C" void kernel_launch(void* const* d_in, const int* in_sizes, int n_in,
                              void* d_out, int out_size, void* d_ws, size_t ws_size,
                              hipStream_t stream) {
    const float* h     = (const float*)d_in[0];
    const float* gW1   = (const float*)d_in[1];
    const float* gb1   = (const float*)d_in[2];
    const float* bn1g  = (const float*)d_in[3];
    const float* bn1b  = (const float*)d_in[4];
    const float* gW2   = (const float*)d_in[5];
    const float* gb2   = (const float*)d_in[6];
    const float* bng   = (const float*)d_in[7];
    const float* bnb   = (const float*)d_in[8];
    const float* prelu = (const float*)d_in[9];
    const float* linW  = (const float*)d_in[10];
    const float* linb  = (const float*)d_in[11];
    const int*   srcv  = (const int*)d_in[12];
    const int*   dstv  = (const int*)d_in[13];
    float* out = (float*)d_out;

    char* base = (char*)d_ws;
    size_t off = 0;
    auto carve = [&](size_t bytes) -> void* {
        void* p = base + off;
        off += (bytes + 255) & ~(size_t)255;
        return p;
    };
    const size_t HB = (size_t)N_NODES * D;
    bf16* hb0   = (bf16*)carve(HB * 2);
    bf16* hb1   = (bf16*)carve(HB * 2);
    bf16* agg   = (bf16*)carve(HB * 2);
    bf16* zb    = (bf16*)carve(HB * 2);
    bf16* ab    = (bf16*)carve(HB * 2);
    bf16* wf    = (bf16*)carve(8 * D * D * 2);
    float* stats = (float*)carve(N_GIN * 2 * 2 * D * 4);
    int* rowptr = (int*)carve((N_NODES + 1) * 4);
    int* cursor = (int*)carve(N_NODES * 4);
    int* csr    = (int*)carve((size_t)N_EDGES * 4);
    int* deg    = (int*)carve(N_NODES * 4);
    int* tmp    = (int*)carve(N_NODES * 4);
    int* bsum   = (int*)carve(256 * 4);
    int* bpre   = (int*)carve(256 * 4);
    float* pooled = (float*)carve(5 * N_GRAPHS * D * 4);
    float* part   = (float*)carve((size_t)N_GRAPHS * PCH * D * 4);

    const int NSTATS = N_GIN * 2 * 2 * D;  // 1536

    k_zero<<<NB, 256, 0, stream>>>(deg, stats, NSTATS);
    k_cast<<<(N_NODES * D / 4 + 255) / 256, 256, 0, stream>>>(h, hb0);
    k_prep<<<8, 256, 0, stream>>>(gW1, gW2, wf);
    k_hist<<<N_EDGES / 256, 256, 0, stream>>>(dstv, deg);
    k_scan1<<<NB, 256, 0, stream>>>(deg, tmp, bsum);
    k_scan2<<<1, 256, 0, stream>>>(bsum, bpre);
    k_scan3<<<NB, 256, 0, stream>>>(tmp, bpre, rowptr, cursor);
    k_scatter<<<N_EDGES / 256, 256, 0, stream>>>(srcv, dstv, cursor, csr);
    k_pool1<<<N_GRAPHS * PCH / 16, 256, 0, stream>>>(hb0, part);
    k_pool2<<<N_GRAPHS, 128, 0, stream>>>(part, pooled);

    bf16* hcur = hb0;
    bf16* hnext = hb1;
    for (int l = 0; l < N_GIN; ++l) {
        float* st1 = stats + (l * 2 + 0) * 2 * D;
        float* st2 = stats + (l * 2 + 1) * 2 * D;
        k_agg<<<N_NODES / 16, 256, 0, stream>>>(hcur, rowptr, csr, agg);
        k_gemm<<<256, 256, 0, stream>>>(agg, wf + l * D * D, gb1 + l * D, zb, st1, st1 + D);
        k_gemm_fused<<<256, 256, 0, stream>>>(zb, wf + (4 + l) * D * D, st1,
                                              bn1g + l * D, bn1b + l * D,
                                              gb2 + l * D, ab, st2, st2 + D);
        k_ew_prelu<<<(N_NODES * D / 8 + 255) / 256, 256, 0, stream>>>(
            ab, st2, bng + l * D, bnb + l * D, prelu, hnext);
        k_pool1<<<N_GRAPHS * PCH / 16, 256, 0, stream>>>(hnext, part);
        k_pool2<<<N_GRAPHS, 128, 0, stream>>>(part, pooled + (size_t)(l + 1) * N_GRAPHS * D);
        bf16* tmpp = hcur; hcur = hnext; hnext = tmpp;
    }
    k_heads<<<5 * N_GRAPHS, 128, 0, stream>>>(pooled, linW, linb, out);
}